// Round 6
// baseline (58.807 us; speedup 1.0000x reference)
//
#include <hip/hip_runtime.h>
#include <hip/hip_bf16.h>

#define BB 8
#define NN 2048
#define FF 128

typedef __bf16 bf16x8 __attribute__((ext_vector_type(8)));
typedef float f32x4 __attribute__((ext_vector_type(4)));

__device__ __forceinline__ void gload_lds16(const void* g, void* l) {
    __builtin_amdgcn_global_load_lds(
        (const __attribute__((address_space(1))) unsigned int*)g,
        (__attribute__((address_space(3))) unsigned int*)l, 16, 0, 0);
}

// ---------------------------------------------------------------------------
// Kernel P (fused prep): blocks [0,4096) bitpack adj -> bmp (1 bit/edge);
// blocks [4096,4608) compute Wh = h @ W, src/dst vectors, and fragB in MFMA
// B-fragment order: fragB[((b*64+J)*8 + ft)*64 + lane][e] =
//   Wh[J*32 + (lane>>4)*8 + e][ft*16 + (lane&15)]
// Repack first in dispatch order so the HBM stream starts immediately.
// ---------------------------------------------------------------------------
__global__ __launch_bounds__(256) void prep_kernel(
    const float* __restrict__ h, const int* __restrict__ adj,
    const float* __restrict__ W, const float* __restrict__ a,
    __bf16* __restrict__ fragB, float* __restrict__ srcg,
    float* __restrict__ dstg, unsigned char* __restrict__ bmp)
{
    __shared__ float  s_h[32][132];
    __shared__ __bf16 s_wh[32][132];
    __shared__ float  s_s[2][32];
    __shared__ float  s_d[2][32];

    const int bidr = blockIdx.x;
    const int t    = threadIdx.x;
    const int w    = t >> 6;
    const int l    = t & 63;

    if (bidr < 4096) {
        // ---- adj bitpack: wave = one row, 4 rows/block ----
        const int row = bidr * 4 + w;
        const int* ar = adj + (size_t)row * NN;
        unsigned char* br = bmp + (size_t)row * 256;
#pragma unroll
        for (int i = 0; i < 4; ++i) {
            const int j0 = i * 512 + l * 8;
            const int4 v0 = *(const int4*)(ar + j0);
            const int4 v1 = *(const int4*)(ar + j0 + 4);
            const unsigned byte =
                  (unsigned)(v0.x > 0)        | ((unsigned)(v0.y > 0) << 1)
                | ((unsigned)(v0.z > 0) << 2) | ((unsigned)(v0.w > 0) << 3)
                | ((unsigned)(v1.x > 0) << 4) | ((unsigned)(v1.y > 0) << 5)
                | ((unsigned)(v1.z > 0) << 6) | ((unsigned)(v1.w > 0) << 7);
            br[i * 64 + l] = (unsigned char)byte;
        }
        return;
    }

    // ---- Wh part (proven wh_kernel, bid in [0,512)) ----
    const int bid = bidr - 4096;
    const int b   = bid >> 6;
    const int J   = bid & 63;
    const int r0  = J * 32;
    const int itile = w & 1;
    const int fh    = w >> 1;
    const int g     = l >> 4;
    const int c16   = l & 15;

#pragma unroll
    for (int i = 0; i < 4; ++i) {
        const int idx = t + i * 256;
        const int r   = idx >> 5;
        const int c4  = idx & 31;
        *(f32x4*)&s_h[r][c4 * 4] =
            *(const f32x4*)(h + (size_t)(b * NN + r0 + r) * FF + c4 * 4);
    }
    __syncthreads();

    const float* hrow = &s_h[itile * 16 + c16][0];
    f32x4 acc[4] = {};

#pragma unroll
    for (int kt = 0; kt < 4; ++kt) {
        const int k0 = kt * 32 + g * 8;
        f32x4 h0 = *(const f32x4*)(hrow + k0);
        f32x4 h1 = *(const f32x4*)(hrow + k0 + 4);
        bf16x8 af;
        af[0]=(__bf16)h0[0]; af[1]=(__bf16)h0[1]; af[2]=(__bf16)h0[2]; af[3]=(__bf16)h0[3];
        af[4]=(__bf16)h1[0]; af[5]=(__bf16)h1[1]; af[6]=(__bf16)h1[2]; af[7]=(__bf16)h1[3];
#pragma unroll
        for (int ft = 0; ft < 4; ++ft) {
            const int c = (fh * 4 + ft) * 16 + c16;
            bf16x8 bf;
#pragma unroll
            for (int e = 0; e < 8; ++e) bf[e] = (__bf16)W[(k0 + e) * FF + c];
            acc[ft] = __builtin_amdgcn_mfma_f32_16x16x32_bf16(af, bf, acc[ft], 0, 0, 0);
        }
    }

    float a1v[4], a2v[4];
#pragma unroll
    for (int ft = 0; ft < 4; ++ft) {
        const int c = (fh * 4 + ft) * 16 + c16;
        a1v[ft] = a[c];
        a2v[ft] = a[FF + c];
    }
#pragma unroll
    for (int r = 0; r < 4; ++r) {
        float s = 0.f, d2 = 0.f;
#pragma unroll
        for (int ft = 0; ft < 4; ++ft) {
            s  += acc[ft][r] * a1v[ft];
            d2 += acc[ft][r] * a2v[ft];
        }
#pragma unroll
        for (int m = 1; m <= 8; m <<= 1) {
            s  += __shfl_xor(s,  m);
            d2 += __shfl_xor(d2, m);
        }
        if (c16 == 0) {
            s_s[fh][itile * 16 + g * 4 + r] = s;
            s_d[fh][itile * 16 + g * 4 + r] = d2;
        }
    }

#pragma unroll
    for (int ft = 0; ft < 4; ++ft)
#pragma unroll
        for (int r = 0; r < 4; ++r)
            s_wh[itile * 16 + g * 4 + r][(fh * 4 + ft) * 16 + c16] = (__bf16)acc[ft][r];

    __syncthreads();

#pragma unroll
    for (int e2 = 0; e2 < 2; ++e2) {
        const int ent  = t + e2 * 256;
        const int ftE  = ent >> 6;
        const int lE   = ent & 63;
        const int rowE = (lE >> 4) * 8;
        const int colE = ftE * 16 + (lE & 15);
        bf16x8 v;
#pragma unroll
        for (int ee = 0; ee < 8; ++ee) v[ee] = s_wh[rowE + ee][colE];
        *(bf16x8*)(fragB + ((size_t)((b * 64 + J) * 8 + ftE) * 64 + lE) * 8) = v;
    }

    if (t < 32) {
        srcg[b * NN + r0 + t] = s_s[0][t] + s_s[1][t];
        dstg[b * NN + r0 + t] = s_d[0][t] + s_d[1][t];
    }
}

// ---------------------------------------------------------------------------
// Kernel B v6: v4 skeleton + bitmask adj + depth-4 frag DMA pipe.
// 4 waves = {it in 0..1} x {jhalf h in 0..1}; 32 steps of 64 j.
//   frag: 4 LDS slots x 16KB via global_load_lds (prefetch distance 3)
//   adj:  1 asm global_load_ubyte per lane per step (bitmap, L1-resident)
// VMEM ledger (per wave): group = 4 DMA + 1 byte = 5 ops; at step top
// outstanding = groups kt..kt+2 (15) -> vmcnt(10) retires exactly group kt;
// then issue group kt+3. Never drains in steady state.
// ---------------------------------------------------------------------------
__global__ __launch_bounds__(256, 2) void attn_kernel(
    const unsigned char* __restrict__ bmp, const __bf16* __restrict__ fragB,
    const float* __restrict__ srcg, const float* __restrict__ dstg,
    float* __restrict__ out)
{
    __shared__ char  s_pipe[65536];   // frag 4 slots x 16KB (tail: combine)
    __shared__ float s_dst[NN];       // 8 KB
    __shared__ float s_ps[2][64];

    const int bid0 = blockIdx.x;
    const int bid  = (bid0 & 7) * 64 + (bid0 >> 3);   // bijective XCD swizzle
    const int b    = bid >> 6;
    const int I0   = (bid & 63) * 32;
    const int t    = threadIdx.x;
    const int w    = t >> 6;
    const int l    = t & 63;
    const int it   = w >> 1;
    const int h    = w & 1;
    const int g    = l >> 4;
    const int c16  = l & 15;

    // sv first: its compiler-inserted wait happens before our DMA ledger starts
    const float sv = srcg[b * NN + I0 + it * 16 + c16];

    // ---- dst staging via DMA (2 ops/wave, retired by first vmcnt(10)) ----
    {
        const char* dsrc = (const char*)(dstg + (size_t)b * NN) + w * 2048 + l * 16;
        char* ddst = (char*)s_dst + w * 2048;
        gload_lds16(dsrc,        ddst);
        gload_lds16(dsrc + 1024, ddst + 1024);
    }

    // ---- per-wave frag chunk pointers (chunks c = w*4+i of each 16KB step) ----
    const char* fragBB = (const char*)fragB + (size_t)b * 524288;
    const char* fS0 = fragBB + ((w*4+0) >> 3) * 8192 + ((w*4+0) & 7) * 1024 + l * 16;
    const char* fS1 = fragBB + ((w*4+1) >> 3) * 8192 + ((w*4+1) & 7) * 1024 + l * 16;
    const char* fS2 = fragBB + ((w*4+2) >> 3) * 8192 + ((w*4+2) & 7) * 1024 + l * 16;
    const char* fS3 = fragBB + ((w*4+3) >> 3) * 8192 + ((w*4+3) & 7) * 1024 + l * 16;
    char* fD0 = s_pipe + (w*4+0) * 1024;
    char* fD1 = s_pipe + (w*4+1) * 1024;
    char* fD2 = s_pipe + (w*4+2) * 1024;
    char* fD3 = s_pipe + (w*4+3) * 1024;

    // bitmap pointer: row = I0+it*16+c16, byte (kt*8 + h*4 + g)
    const unsigned char* bp =
        bmp + (size_t)(b * NN + I0 + it * 16 + c16) * 256 + h * 4 + g;

#define STAGE_G(kt_, BT_) {                                                   \
        const int sl_ = (kt_) & 3;                                            \
        gload_lds16(fS0 + (size_t)(kt_) * 16384, fD0 + sl_ * 16384);          \
        gload_lds16(fS1 + (size_t)(kt_) * 16384, fD1 + sl_ * 16384);          \
        gload_lds16(fS2 + (size_t)(kt_) * 16384, fD2 + sl_ * 16384);          \
        gload_lds16(fS3 + (size_t)(kt_) * 16384, fD3 + sl_ * 16384);          \
        asm volatile("global_load_ubyte %0, %1, off"                          \
                     : "=&v"(BT_) : "v"(bp + (size_t)(kt_) * 8)); }

#define STEPC(kt_, BT_) {                                                     \
        const int j0_ = (kt_) * 64 + h * 32 + g * 8;                          \
        const f32x4 d0_ = *(const f32x4*)(s_dst + j0_);                       \
        const f32x4 d1_ = *(const f32x4*)(s_dst + j0_ + 4);                   \
        const float dv_[8] = {d0_[0], d0_[1], d0_[2], d0_[3],                 \
                              d1_[0], d1_[1], d1_[2], d1_[3]};                \
        const unsigned msk_ = BT_;                                            \
        bf16x8 af_;                                                           \
        _Pragma("unroll")                                                     \
        for (int e = 0; e < 8; ++e) {                                         \
            float x = sv + dv_[e];                                            \
            x = fmaxf(x, 0.2f * x);                                           \
            float p = __expf(x);                                              \
            p = ((msk_ >> e) & 1u) ? p : 0.f;                                 \
            psum += p;                                                        \
            af_[e] = (__bf16)p;                                               \
        }                                                                     \
        const char* ftile_ = s_pipe + ((kt_) & 3) * 16384 + h * 8192 + l * 16;\
        _Pragma("unroll")                                                     \
        for (int ft = 0; ft < 8; ++ft) {                                      \
            const bf16x8 bf_ = *(const bf16x8*)(ftile_ + ft * 1024);          \
            acc[ft] = __builtin_amdgcn_mfma_f32_16x16x32_bf16(af_, bf_, acc[ft], 0, 0, 0); \
        } }

#define BARRIER_W(VMC_) {                                                     \
        asm volatile("s_waitcnt vmcnt(" VMC_ ") lgkmcnt(0)" ::: "memory");    \
        __builtin_amdgcn_s_barrier();                                         \
        asm volatile("" ::: "memory"); }

    f32x4 acc[8] = {};
    float psum = 0.f;
    unsigned bt[4];

    // prologue: groups 0..2 (15 ops) on top of 2 dst DMAs = 17 outstanding
    STAGE_G(0, bt[0]);
    STAGE_G(1, bt[1]);
    STAGE_G(2, bt[2]);

#pragma unroll 4
    for (int kt = 0; kt < 28; ++kt) {
        BARRIER_W("10")                    // retires dst DMAs (once) + group kt
        STAGE_G(kt + 3, bt[(kt + 3) & 3]);
        STEPC(kt, bt[kt & 3]);
    }
    BARRIER_W("10")  STAGE_G(31, bt[3]);  STEPC(28, bt[0]);
    BARRIER_W("10")  STEPC(29, bt[1]);
    BARRIER_W("5")   STEPC(30, bt[2]);
    BARRIER_W("0")   STEPC(31, bt[3]);

    // per-wave row-sum over its j-half (replicated across g)
    psum += __shfl_xor(psum, 16);
    psum += __shfl_xor(psum, 32);

    // ---- combine j-halves (reuse pipe LDS; all DMA retired, vmcnt==0) ----
    __syncthreads();
    float* s_comb = (float*)s_pipe;          // [2][64][33]
    if (h == 1) {
        float* cb = s_comb + (it * 64 + l) * 33;
#pragma unroll
        for (int ft = 0; ft < 8; ++ft)
#pragma unroll
            for (int r = 0; r < 4; ++r) cb[ft * 4 + r] = acc[ft][r];
        s_ps[it][l] = psum;
    }
    __syncthreads();
    if (h == 0) {
        psum += s_ps[it][l];
        const float* cb = s_comb + (it * 64 + l) * 33;
#pragma unroll
        for (int ft = 0; ft < 8; ++ft)
#pragma unroll
            for (int r = 0; r < 4; ++r) acc[ft][r] += cb[ft * 4 + r];

#pragma unroll
        for (int r = 0; r < 4; ++r) {
            const float dinv = 1.f / __shfl(psum, g * 4 + r);
            const int row = I0 + it * 16 + g * 4 + r;
            float* orow = out + (size_t)(b * NN + row) * FF + c16;
#pragma unroll
            for (int ft = 0; ft < 8; ++ft) orow[ft * 16] = acc[ft][r] * dinv;
        }
    }
#undef STAGE_G
#undef STEPC
#undef BARRIER_W
}

// ---------------------------------------------------------------------------
extern "C" void kernel_launch(void* const* d_in, const int* in_sizes, int n_in,
                              void* d_out, int out_size, void* d_ws, size_t ws_size,
                              hipStream_t stream)
{
    const float* h   = (const float*)d_in[0];
    const int*   adj = (const int*)d_in[1];
    const float* W   = (const float*)d_in[2];
    const float* a   = (const float*)d_in[3];
    float* out = (float*)d_out;

    char* ws = (char*)d_ws;
    __bf16*        fragB = (__bf16*)ws;                       // 4 MiB
    unsigned char* bmp   = (unsigned char*)(ws + (4 << 20));  // 4 MiB
    float* srcg = (float*)(ws + (8 << 20));                   // 64 KiB
    float* dstg = (float*)(ws + (8 << 20) + (64 << 10));      // 64 KiB

    prep_kernel<<<4608, 256, 0, stream>>>(h, adj, W, a, fragB, srcg, dstg, bmp);
    attn_kernel<<<512, 256, 0, stream>>>(bmp, fragB, srcg, dstg, out);
}

// Round 7
// 43.018 us; speedup vs baseline: 1.3670x; 1.3670x over previous
//
#include <hip/hip_runtime.h>
#include <hip/hip_bf16.h>

#define BB 8
#define NN 2048
#define FF 128

typedef __bf16 bf16x8 __attribute__((ext_vector_type(8)));
typedef float f32x4 __attribute__((ext_vector_type(4)));
typedef float f32x16 __attribute__((ext_vector_type(16)));

__device__ __forceinline__ void gload_lds16(const void* g, void* l) {
    __builtin_amdgcn_global_load_lds(
        (const __attribute__((address_space(1))) unsigned int*)g,
        (__attribute__((address_space(3))) unsigned int*)l, 16, 0, 0);
}

// ---------------------------------------------------------------------------
// Kernel A: Wh = h @ W (bf16 MFMA), src/dst rowvecs, fragB packed in
// 32x32x16 MFMA **B-fragment** order:
//   tile T = (b*128 + jt)*4 + ft   (jt: 16-row block of Wh, ft: 32-col block)
//   fragB[T*64 + lane][e] = Wh[jt*16 + (lane>>5)*8 + e][ft*32 + (lane&31)]
// ---------------------------------------------------------------------------
__global__ __launch_bounds__(256) void wh_kernel(
    const float* __restrict__ h, const float* __restrict__ W,
    const float* __restrict__ a, __bf16* __restrict__ fragB,
    float* __restrict__ srcg, float* __restrict__ dstg)
{
    __shared__ float  s_h[32][132];
    __shared__ __bf16 s_wh[32][132];
    __shared__ float  s_s[2][32];
    __shared__ float  s_d[2][32];

    const int bid = blockIdx.x;
    const int b   = bid >> 6;
    const int J   = bid & 63;
    const int r0  = J * 32;
    const int t   = threadIdx.x;
    const int w   = t >> 6;
    const int l   = t & 63;
    const int itile = w & 1;
    const int fh    = w >> 1;
    const int g     = l >> 4;
    const int c16   = l & 15;

#pragma unroll
    for (int i = 0; i < 4; ++i) {
        const int idx = t + i * 256;
        const int r   = idx >> 5;
        const int c4  = idx & 31;
        *(f32x4*)&s_h[r][c4 * 4] =
            *(const f32x4*)(h + (size_t)(b * NN + r0 + r) * FF + c4 * 4);
    }
    __syncthreads();

    const float* hrow = &s_h[itile * 16 + c16][0];
    f32x4 acc[4] = {};

#pragma unroll
    for (int kt = 0; kt < 4; ++kt) {
        const int k0 = kt * 32 + g * 8;
        f32x4 h0 = *(const f32x4*)(hrow + k0);
        f32x4 h1 = *(const f32x4*)(hrow + k0 + 4);
        bf16x8 af;
        af[0]=(__bf16)h0[0]; af[1]=(__bf16)h0[1]; af[2]=(__bf16)h0[2]; af[3]=(__bf16)h0[3];
        af[4]=(__bf16)h1[0]; af[5]=(__bf16)h1[1]; af[6]=(__bf16)h1[2]; af[7]=(__bf16)h1[3];
#pragma unroll
        for (int ft = 0; ft < 4; ++ft) {
            const int c = (fh * 4 + ft) * 16 + c16;
            bf16x8 bf;
#pragma unroll
            for (int e = 0; e < 8; ++e) bf[e] = (__bf16)W[(k0 + e) * FF + c];
            acc[ft] = __builtin_amdgcn_mfma_f32_16x16x32_bf16(af, bf, acc[ft], 0, 0, 0);
        }
    }

    float a1v[4], a2v[4];
#pragma unroll
    for (int ft = 0; ft < 4; ++ft) {
        const int c = (fh * 4 + ft) * 16 + c16;
        a1v[ft] = a[c];
        a2v[ft] = a[FF + c];
    }
#pragma unroll
    for (int r = 0; r < 4; ++r) {
        float s = 0.f, d2 = 0.f;
#pragma unroll
        for (int ft = 0; ft < 4; ++ft) {
            s  += acc[ft][r] * a1v[ft];
            d2 += acc[ft][r] * a2v[ft];
        }
#pragma unroll
        for (int m = 1; m <= 8; m <<= 1) {
            s  += __shfl_xor(s,  m);
            d2 += __shfl_xor(d2, m);
        }
        if (c16 == 0) {
            s_s[fh][itile * 16 + g * 4 + r] = s;
            s_d[fh][itile * 16 + g * 4 + r] = d2;
        }
    }

#pragma unroll
    for (int ft = 0; ft < 4; ++ft)
#pragma unroll
        for (int r = 0; r < 4; ++r)
            s_wh[itile * 16 + g * 4 + r][(fh * 4 + ft) * 16 + c16] = (__bf16)acc[ft][r];

    __syncthreads();

    // re-read in 32x32 B-fragment order and store (16B per lane, coalesced)
#pragma unroll
    for (int e2 = 0; e2 < 2; ++e2) {
        const int ent  = t + e2 * 256;   // 0..511 = tile(3b) * 64 + lane
        const int tile = ent >> 6;       // jl*4 + ft
        const int jl   = tile >> 2;
        const int ft   = tile & 3;
        const int lE   = ent & 63;
        const int rowE = jl * 16 + (lE >> 5) * 8;
        const int colE = ft * 32 + (lE & 31);
        bf16x8 v;
#pragma unroll
        for (int ee = 0; ee < 8; ++ee) v[ee] = s_wh[rowE + ee][colE];
        *(bf16x8*)(fragB + (((size_t)(b * 128 + J * 2 + jl) * 4 + ft) * 64 + lE) * 8) = v;
    }

    if (t < 32) {
        srcg[b * NN + r0 + t] = s_s[0][t] + s_s[1][t];
        dstg[b * NN + r0 + t] = s_d[0][t] + s_d[1][t];
    }
}

// ---------------------------------------------------------------------------
// Kernel B v7: wave-private DMA pipelines, ZERO inner barriers.
// 4 waves = 4 j-quarters (512 j each), 32 steps of 16 j, M=32 via
// v_mfma_f32_32x32x16_bf16 (no frag/exp duplication across waves).
// Per-wave vmcnt ledger (only DMA ops exist): per step issue
// {adj(kt+3): 2 ops, frag(kt+1): 4 ops}, then s_waitcnt vmcnt(6) ->
// retires adj(kt)+frag(kt). adj distance 3 (HBM), frag distance 1 (L2).
// adj LDS reads bank-spread by source pre-swizzle chunk^=(row&3).
// Tail: 4-way j-partial combine in LDS (stride 17 = conflict-free).
// ---------------------------------------------------------------------------
__global__ __launch_bounds__(256, 2) void attn_kernel(
    const int* __restrict__ adj, const __bf16* __restrict__ fragB,
    const float* __restrict__ srcg, const float* __restrict__ dstg,
    float* __restrict__ out)
{
    __shared__ char  s_all[77824];   // adj 4x2K/wave | frag 2x4K/wave | dst 2K | src 1K
    __shared__ float s_ps[4][32];

    const int bid0 = blockIdx.x;
    const int bid  = (bid0 & 7) * 64 + (bid0 >> 3);   // bijective XCD swizzle
    const int b    = bid >> 6;
    const int I0   = (bid & 63) * 32;
    const int t    = threadIdx.x;
    const int q    = t >> 6;                  // wave = j-quarter
    const int l    = t & 63;
    const int r31  = l & 31;
    const int hi   = l >> 5;

    char* awave = s_all + q * 8192;           // 4 slots x 2048
    char* fwave = s_all + 32768 + q * 8192;   // 2 slots x 4096
    char* dstw  = s_all + 65536 + q * 2048;
    char* srcw  = s_all + 73728 + q * 1024;

    // adj op c covers rows c*16+(l>>2), swizzled 16B-chunk (l&3)^((l>>2)&3)
    const char* aBase0 = (const char*)adj
        + ((size_t)(b * NN + I0 + (l >> 2)) * NN + q * 512) * 4
        + ((l & 3) ^ ((l >> 2) & 3)) * 16;
    const char* aBase1 = aBase0 + (size_t)16 * NN * 4;
    const char* fBase  = (const char*)fragB
        + ((size_t)(b * 128 + q * 32) * 4) * 1024 + (size_t)l * 16;
    const char* dSrc   = (const char*)(dstg + (size_t)b * NN + q * 512) + l * 16;
    const char* sSrc   = (const char*)(srcg + (size_t)b * NN + I0) + l * 16; // lanes>7 read past (in-ws, unused)

#define ISSUE_A(ki_, sl_) {                                                   \
        gload_lds16(aBase0 + (size_t)(ki_) * 64, awave + (sl_) * 2048);       \
        gload_lds16(aBase1 + (size_t)(ki_) * 64, awave + (sl_) * 2048 + 1024); }
#define ISSUE_F(ki_, sl_) {                                                   \
        const char* fp_ = fBase + (size_t)(ki_) * 4096;                       \
        gload_lds16(fp_,        fwave + (sl_) * 4096);                        \
        gload_lds16(fp_ + 1024, fwave + (sl_) * 4096 + 1024);                 \
        gload_lds16(fp_ + 2048, fwave + (sl_) * 4096 + 2048);                 \
        gload_lds16(fp_ + 3072, fwave + (sl_) * 4096 + 3072); }

    // prologue ledger: D,D,S (3) + A0,A1,A2 (6) + F0 (4) = 13 ops
    gload_lds16(dSrc,        dstw);
    gload_lds16(dSrc + 1024, dstw + 1024);
    gload_lds16(sSrc,        srcw);
    ISSUE_A(0, 0); ISSUE_A(1, 1); ISSUE_A(2, 2);
    ISSUE_F(0, 0);

    asm volatile("s_waitcnt vmcnt(10)" ::: "memory");   // retire D,D,S
    __builtin_amdgcn_sched_barrier(0);
    const float sv = *(const float*)(srcw + r31 * 4);

    f32x16 acc0 = {}, acc1 = {}, acc2 = {}, acc3 = {};
    float psum = 0.f;

#pragma unroll 4
    for (int kt = 0; kt < 32; ++kt) {
        const int kA = (kt + 3 < 32) ? kt + 3 : 31;   // clamped dummy keeps ledger
        const int kF = (kt + 1 < 32) ? kt + 1 : 31;
        ISSUE_A(kA, (kt + 3) & 3);
        ISSUE_F(kF, (kt + 1) & 1);
        asm volatile("s_waitcnt vmcnt(6)" ::: "memory");  // adj(kt)+frag(kt) ready
        __builtin_amdgcn_sched_barrier(0);

        const char* asl = awave + (kt & 3) * 2048 + r31 * 64;
        const int4 A0 = *(const int4*)(asl + (((hi * 2)    ) ^ (r31 & 3)) * 16);
        const int4 A1 = *(const int4*)(asl + (((hi * 2) + 1) ^ (r31 & 3)) * 16);
        const f32x4 d0 = *(const f32x4*)(dstw + kt * 64 + hi * 32);
        const f32x4 d1 = *(const f32x4*)(dstw + kt * 64 + hi * 32 + 16);
        const int   am[8] = {A0.x, A0.y, A0.z, A0.w, A1.x, A1.y, A1.z, A1.w};
        const float dv[8] = {d0[0], d0[1], d0[2], d0[3], d1[0], d1[1], d1[2], d1[3]};

        bf16x8 af;
#pragma unroll
        for (int e = 0; e < 8; ++e) {
            float x = sv + dv[e];
            x = fmaxf(x, 0.2f * x);          // leaky_relu 0.2
            float p = __expf(x);             // bounded, no max-sub needed
            p = (am[e] > 0) ? p : 0.f;
            psum += p;
            af[e] = (__bf16)p;
        }

        const char* fsl = fwave + (kt & 1) * 4096 + l * 16;
        const bf16x8 b0 = *(const bf16x8*)(fsl);
        const bf16x8 b1 = *(const bf16x8*)(fsl + 1024);
        const bf16x8 b2 = *(const bf16x8*)(fsl + 2048);
        const bf16x8 b3 = *(const bf16x8*)(fsl + 3072);
        acc0 = __builtin_amdgcn_mfma_f32_32x32x16_bf16(af, b0, acc0, 0, 0, 0);
        acc1 = __builtin_amdgcn_mfma_f32_32x32x16_bf16(af, b1, acc1, 0, 0, 0);
        acc2 = __builtin_amdgcn_mfma_f32_32x32x16_bf16(af, b2, acc2, 0, 0, 0);
        acc3 = __builtin_amdgcn_mfma_f32_32x32x16_bf16(af, b3, acc3, 0, 0, 0);
    }
#undef ISSUE_A
#undef ISSUE_F

    asm volatile("s_waitcnt vmcnt(0)" ::: "memory");  // drain dummies before LDS reuse

    // denom partial: lanes l and l^32 cover the same row
    psum += __shfl_xor(psum, 32);
    if (l < 32) s_ps[q][l] = psum;

    // ---- 4-way j-partial combine (reuse pipe LDS: [4 q][4 ft][64][17]) ----
    __syncthreads();
    float* comb = (float*)s_all;
    {
        float* cb = comb + ((q * 4 + 0) * 64 + l) * 17;
#pragma unroll
        for (int r = 0; r < 16; ++r) cb[r] = acc0[r];
        cb = comb + ((q * 4 + 1) * 64 + l) * 17;
#pragma unroll
        for (int r = 0; r < 16; ++r) cb[r] = acc1[r];
        cb = comb + ((q * 4 + 2) * 64 + l) * 17;
#pragma unroll
        for (int r = 0; r < 16; ++r) cb[r] = acc2[r];
        cb = comb + ((q * 4 + 3) * 64 + l) * 17;
#pragma unroll
        for (int r = 0; r < 16; ++r) cb[r] = acc3[r];
    }
    __syncthreads();

    // wave q owns output ft-tile q
    f32x16 tot;
#pragma unroll
    for (int r = 0; r < 16; ++r)
        tot[r] = comb[((0 * 4 + q) * 64 + l) * 17 + r]
               + comb[((1 * 4 + q) * 64 + l) * 17 + r]
               + comb[((2 * 4 + q) * 64 + l) * 17 + r]
               + comb[((3 * 4 + q) * 64 + l) * 17 + r];

    const float dtot = s_ps[0][r31] + s_ps[1][r31] + s_ps[2][r31] + s_ps[3][r31];
    const float rin  = 1.f / dtot;            // lane r31 holds row r31's denom

    // C layout (32x32): col = l&31, row = (r&3) + 8*(r>>2) + 4*hi
#pragma unroll
    for (int r = 0; r < 16; ++r) {
        const int row  = (r & 3) + 8 * (r >> 2) + 4 * hi;
        const float dv2 = __shfl(rin, row);
        out[(size_t)(b * NN + I0 + row) * FF + q * 32 + r31] = tot[r] * dv2;
    }
}

// ---------------------------------------------------------------------------
extern "C" void kernel_launch(void* const* d_in, const int* in_sizes, int n_in,
                              void* d_out, int out_size, void* d_ws, size_t ws_size,
                              hipStream_t stream)
{
    const float* h   = (const float*)d_in[0];
    const int*   adj = (const int*)d_in[1];
    const float* W   = (const float*)d_in[2];
    const float* a   = (const float*)d_in[3];
    float* out = (float*)d_out;

    char* ws = (char*)d_ws;
    __bf16* fragB = (__bf16*)ws;                              // 4 MiB
    float*  srcg  = (float*)(ws + (4 << 20));                 // 64 KiB
    float*  dstg  = (float*)(ws + (4 << 20) + (64 << 10));    // 64 KiB

    wh_kernel<<<512, 256, 0, stream>>>(h, W, a, fragB, srcg, dstg);
    attn_kernel<<<512, 256, 0, stream>>>(adj, fragB, srcg, dstg, out);
}

// Round 8
// 42.316 us; speedup vs baseline: 1.3897x; 1.0166x over previous
//
#include <hip/hip_runtime.h>
#include <hip/hip_bf16.h>

#define BB 8
#define NN 2048
#define FF 128

typedef __bf16 bf16x8 __attribute__((ext_vector_type(8)));
typedef float f32x4 __attribute__((ext_vector_type(4)));
typedef float f32x16 __attribute__((ext_vector_type(16)));

__device__ __forceinline__ void gload_lds16(const void* g, void* l) {
    __builtin_amdgcn_global_load_lds(
        (const __attribute__((address_space(1))) unsigned int*)g,
        (__attribute__((address_space(3))) unsigned int*)l, 16, 0, 0);
}

// ---------------------------------------------------------------------------
// Kernel A: Wh = h @ W (bf16 MFMA), src/dst rowvecs, fragB packed in
// 32x32x16 MFMA **B-fragment** order:
//   tile T = (b*128 + jt)*4 + ft   (jt: 16-row block of Wh, ft: 32-col block)
//   fragB[T*64 + lane][e] = Wh[jt*16 + (lane>>5)*8 + e][ft*32 + (lane&31)]
// (unchanged from round 7 — passed refcheck)
// ---------------------------------------------------------------------------
__global__ __launch_bounds__(256) void wh_kernel(
    const float* __restrict__ h, const float* __restrict__ W,
    const float* __restrict__ a, __bf16* __restrict__ fragB,
    float* __restrict__ srcg, float* __restrict__ dstg)
{
    __shared__ float  s_h[32][132];
    __shared__ __bf16 s_wh[32][132];
    __shared__ float  s_s[2][32];
    __shared__ float  s_d[2][32];

    const int bid = blockIdx.x;
    const int b   = bid >> 6;
    const int J   = bid & 63;
    const int r0  = J * 32;
    const int t   = threadIdx.x;
    const int w   = t >> 6;
    const int l   = t & 63;
    const int itile = w & 1;
    const int fh    = w >> 1;
    const int g     = l >> 4;
    const int c16   = l & 15;

#pragma unroll
    for (int i = 0; i < 4; ++i) {
        const int idx = t + i * 256;
        const int r   = idx >> 5;
        const int c4  = idx & 31;
        *(f32x4*)&s_h[r][c4 * 4] =
            *(const f32x4*)(h + (size_t)(b * NN + r0 + r) * FF + c4 * 4);
    }
    __syncthreads();

    const float* hrow = &s_h[itile * 16 + c16][0];
    f32x4 acc[4] = {};

#pragma unroll
    for (int kt = 0; kt < 4; ++kt) {
        const int k0 = kt * 32 + g * 8;
        f32x4 h0 = *(const f32x4*)(hrow + k0);
        f32x4 h1 = *(const f32x4*)(hrow + k0 + 4);
        bf16x8 af;
        af[0]=(__bf16)h0[0]; af[1]=(__bf16)h0[1]; af[2]=(__bf16)h0[2]; af[3]=(__bf16)h0[3];
        af[4]=(__bf16)h1[0]; af[5]=(__bf16)h1[1]; af[6]=(__bf16)h1[2]; af[7]=(__bf16)h1[3];
#pragma unroll
        for (int ft = 0; ft < 4; ++ft) {
            const int c = (fh * 4 + ft) * 16 + c16;
            bf16x8 bf;
#pragma unroll
            for (int e = 0; e < 8; ++e) bf[e] = (__bf16)W[(k0 + e) * FF + c];
            acc[ft] = __builtin_amdgcn_mfma_f32_16x16x32_bf16(af, bf, acc[ft], 0, 0, 0);
        }
    }

    float a1v[4], a2v[4];
#pragma unroll
    for (int ft = 0; ft < 4; ++ft) {
        const int c = (fh * 4 + ft) * 16 + c16;
        a1v[ft] = a[c];
        a2v[ft] = a[FF + c];
    }
#pragma unroll
    for (int r = 0; r < 4; ++r) {
        float s = 0.f, d2 = 0.f;
#pragma unroll
        for (int ft = 0; ft < 4; ++ft) {
            s  += acc[ft][r] * a1v[ft];
            d2 += acc[ft][r] * a2v[ft];
        }
#pragma unroll
        for (int m = 1; m <= 8; m <<= 1) {
            s  += __shfl_xor(s,  m);
            d2 += __shfl_xor(d2, m);
        }
        if (c16 == 0) {
            s_s[fh][itile * 16 + g * 4 + r] = s;
            s_d[fh][itile * 16 + g * 4 + r] = d2;
        }
    }

#pragma unroll
    for (int ft = 0; ft < 4; ++ft)
#pragma unroll
        for (int r = 0; r < 4; ++r)
            s_wh[itile * 16 + g * 4 + r][(fh * 4 + ft) * 16 + c16] = (__bf16)acc[ft][r];

    __syncthreads();

#pragma unroll
    for (int e2 = 0; e2 < 2; ++e2) {
        const int ent  = t + e2 * 256;
        const int tile = ent >> 6;
        const int jl   = tile >> 2;
        const int ft   = tile & 3;
        const int lE   = ent & 63;
        const int rowE = jl * 16 + (lE >> 5) * 8;
        const int colE = ft * 32 + (lE & 31);
        bf16x8 v;
#pragma unroll
        for (int ee = 0; ee < 8; ++ee) v[ee] = s_wh[rowE + ee][colE];
        *(bf16x8*)(fragB + (((size_t)(b * 128 + J * 2 + jl) * 4 + ft) * 64 + lE) * 8) = v;
    }

    if (t < 32) {
        srcg[b * NN + r0 + t] = s_s[0][t] + s_s[1][t];
        dstg[b * NN + r0 + t] = s_d[0][t] + s_d[1][t];
    }
}

// ---------------------------------------------------------------------------
// Kernel B v8: v7 structure with a CORRECT uniform-age vmcnt ledger.
// 4 waves = 4 j-quarters, 32 steps of 16 j, M=32 via mfma_f32_32x32x16_bf16.
// Per step: issue F(kt+1) [4 ops], A(kt+2) [2 ops], then s_waitcnt vmcnt(8)
//   -> retires exactly {A(kt), F(kt)}; adj age 2 steps (HBM-safe), frag age
//   1 step (L2-safe). Zero inner barriers; all pipes wave-private.
// adj LDS layout: slot s = (c&1)*64 + (c>>1)*32 + r  (16B units) so both
//   reads are lane-sequential (lane L -> byte L*16 / 1024+L*16): conflict-free.
// ---------------------------------------------------------------------------
__global__ __launch_bounds__(256, 2) void attn_kernel(
    const int* __restrict__ adj, const __bf16* __restrict__ fragB,
    const float* __restrict__ srcg, const float* __restrict__ dstg,
    float* __restrict__ out)
{
    __shared__ char s_all[74240];
    // [0,32768):      adj  4 slots x 2048 per wave (q*8192)
    // [32768,65536):  frag 2 slots x 4096 per wave (q*8192)
    // [65536,73728):  dst  2048 per wave
    // [73728,74240):  s_ps (tail)
    // tail combine reuses [0,69632)

    const int bid0 = blockIdx.x;
    const int bid  = (bid0 & 7) * 64 + (bid0 >> 3);   // bijective XCD swizzle
    const int b    = bid >> 6;
    const int I0   = (bid & 63) * 32;
    const int t    = threadIdx.x;
    const int q    = t >> 6;                  // wave = j-quarter
    const int l    = t & 63;
    const int r31  = l & 31;
    const int hi   = l >> 5;

    char* awave = s_all + q * 8192;
    char* fwave = s_all + 32768 + q * 8192;
    char* dstw  = s_all + 65536 + q * 2048;
    float* s_ps = (float*)(s_all + 73728);

    // ---- plain src load, fully drained BEFORE the DMA ledger starts ----
    const float sv = srcg[b * NN + I0 + r31];
    asm volatile("s_waitcnt vmcnt(0) lgkmcnt(0)" ::: "memory");

    // adj source: lane s covers (row = s&31, chunk c = 2*(s>>5) [+1 for op1]);
    // chunk c = 4 j's = 16 B at row-byte q*2048 + kt*64 + c*16.
    const char* aSrc = (const char*)adj
        + ((size_t)(b * NN + I0 + r31) * NN + q * 512) * 4 + hi * 32;
    const char* fBase = (const char*)fragB
        + (size_t)(b * 128 + q * 32) * 4096 + (size_t)l * 16;
    const char* dSrc = (const char*)(dstg + (size_t)b * NN + q * 512) + l * 16;

#define ISSUE_A(ki_, sl_) {                                                   \
        const char* pa_ = aSrc + (size_t)(ki_) * 64;                          \
        gload_lds16(pa_,      awave + (sl_) * 2048 + l * 16);                 \
        gload_lds16(pa_ + 16, awave + (sl_) * 2048 + 1024 + l * 16); }
#define ISSUE_F(ki_, sl_) {                                                   \
        const char* pf_ = fBase + (size_t)(ki_) * 4096;                       \
        char* fd_ = fwave + (sl_) * 4096 + l * 16;                            \
        gload_lds16(pf_,        fd_);                                         \
        gload_lds16(pf_ + 1024, fd_ + 1024);                                  \
        gload_lds16(pf_ + 2048, fd_ + 2048);                                  \
        gload_lds16(pf_ + 3072, fd_ + 3072); }

    // prologue ledger (issue order matters): dst(2), A0(2), F0(4), A1(2)
    gload_lds16(dSrc,        dstw + l * 16);
    gload_lds16(dSrc + 1024, dstw + 1024 + l * 16);
    ISSUE_A(0, 0);
    ISSUE_F(0, 0);
    ISSUE_A(1, 1);

    f32x16 acc0 = {}, acc1 = {}, acc2 = {}, acc3 = {};
    float psum = 0.f;

#pragma unroll 4
    for (int kt = 0; kt < 32; ++kt) {
        const int kF = (kt + 1 < 32) ? kt + 1 : 31;   // clamped dummies keep
        const int kA = (kt + 2 < 32) ? kt + 2 : 31;   // the ledger uniform
        ISSUE_F(kF, (kt + 1) & 1);
        ISSUE_A(kA, (kt + 2) & 3);
        // retires exactly A(kt) [age 2 steps] + F(kt) [age 1 step]
        asm volatile("s_waitcnt vmcnt(8)" ::: "memory");
        __builtin_amdgcn_sched_barrier(0);

        // adj: two lane-sequential b128 reads (conflict-free)
        const char* asl = awave + (kt & 3) * 2048 + l * 16;
        const int4 A0 = *(const int4*)(asl);
        const int4 A1 = *(const int4*)(asl + 1024);
        // dst: broadcast reads of this step's 16-j window
        const f32x4 d0 = *(const f32x4*)(dstw + kt * 64 + hi * 32);
        const f32x4 d1 = *(const f32x4*)(dstw + kt * 64 + hi * 32 + 16);
        const int   am[8] = {A0.x, A0.y, A0.z, A0.w, A1.x, A1.y, A1.z, A1.w};
        const float dv[8] = {d0[0], d0[1], d0[2], d0[3], d1[0], d1[1], d1[2], d1[3]};

        bf16x8 af;
#pragma unroll
        for (int e = 0; e < 8; ++e) {
            float x = sv + dv[e];
            x = fmaxf(x, 0.2f * x);          // leaky_relu 0.2
            float p = __expf(x);             // bounded, no max-sub needed
            p = (am[e] > 0) ? p : 0.f;
            psum += p;
            af[e] = (__bf16)p;
        }

        const char* fsl = fwave + (kt & 1) * 4096 + l * 16;
        const bf16x8 b0 = *(const bf16x8*)(fsl);
        const bf16x8 b1 = *(const bf16x8*)(fsl + 1024);
        const bf16x8 b2 = *(const bf16x8*)(fsl + 2048);
        const bf16x8 b3 = *(const bf16x8*)(fsl + 3072);
        acc0 = __builtin_amdgcn_mfma_f32_32x32x16_bf16(af, b0, acc0, 0, 0, 0);
        acc1 = __builtin_amdgcn_mfma_f32_32x32x16_bf16(af, b1, acc1, 0, 0, 0);
        acc2 = __builtin_amdgcn_mfma_f32_32x32x16_bf16(af, b2, acc2, 0, 0, 0);
        acc3 = __builtin_amdgcn_mfma_f32_32x32x16_bf16(af, b3, acc3, 0, 0, 0);
    }
#undef ISSUE_A
#undef ISSUE_F

    asm volatile("s_waitcnt vmcnt(0)" ::: "memory");  // drain dummies before LDS reuse

    // denom partial: lanes l and l^32 cover the same row, disjoint j
    psum += __shfl_xor(psum, 32);
    if (l < 32) s_ps[q * 32 + l] = psum;

    // ---- 4-way j-partial combine (reuse pipe LDS: [4 q][4 ft][64][17]) ----
    __syncthreads();
    float* comb = (float*)s_all;
    {
        float* cb = comb + ((q * 4 + 0) * 64 + l) * 17;
#pragma unroll
        for (int r = 0; r < 16; ++r) cb[r] = acc0[r];
        cb = comb + ((q * 4 + 1) * 64 + l) * 17;
#pragma unroll
        for (int r = 0; r < 16; ++r) cb[r] = acc1[r];
        cb = comb + ((q * 4 + 2) * 64 + l) * 17;
#pragma unroll
        for (int r = 0; r < 16; ++r) cb[r] = acc2[r];
        cb = comb + ((q * 4 + 3) * 64 + l) * 17;
#pragma unroll
        for (int r = 0; r < 16; ++r) cb[r] = acc3[r];
    }
    __syncthreads();

    // wave q owns output ft-tile q
    f32x16 tot;
#pragma unroll
    for (int r = 0; r < 16; ++r)
        tot[r] = comb[((0 * 4 + q) * 64 + l) * 17 + r]
               + comb[((1 * 4 + q) * 64 + l) * 17 + r]
               + comb[((2 * 4 + q) * 64 + l) * 17 + r]
               + comb[((3 * 4 + q) * 64 + l) * 17 + r];

    const float dtot = s_ps[0 * 32 + r31] + s_ps[1 * 32 + r31]
                     + s_ps[2 * 32 + r31] + s_ps[3 * 32 + r31];
    const float rin  = 1.f / dtot;

    // C layout (32x32): col = l&31, row = (r&3) + 8*(r>>2) + 4*hi
#pragma unroll
    for (int r = 0; r < 16; ++r) {
        const int row  = (r & 3) + 8 * (r >> 2) + 4 * hi;
        const float dv2 = __shfl(rin, row);
        out[(size_t)(b * NN + I0 + row) * FF + q * 32 + r31] = tot[r] * dv2;
    }
}

// ---------------------------------------------------------------------------
extern "C" void kernel_launch(void* const* d_in, const int* in_sizes, int n_in,
                              void* d_out, int out_size, void* d_ws, size_t ws_size,
                              hipStream_t stream)
{
    const float* h   = (const float*)d_in[0];
    const int*   adj = (const int*)d_in[1];
    const float* W   = (const float*)d_in[2];
    const float* a   = (const float*)d_in[3];
    float* out = (float*)d_out;

    char* ws = (char*)d_ws;
    __bf16* fragB = (__bf16*)ws;                              // 4 MiB
    float*  srcg  = (float*)(ws + (4 << 20));                 // 64 KiB
    float*  dstg  = (float*)(ws + (4 << 20) + (64 << 10));    // 64 KiB

    wh_kernel<<<512, 256, 0, stream>>>(h, W, a, fragB, srcg, dstg);
    attn_kernel<<<512, 256, 0, stream>>>(adj, fragB, srcg, dstg, out);
}